// Round 5
// baseline (392.702 us; speedup 1.0000x reference)
//
#include <hip/hip_runtime.h>

typedef unsigned short u16;
typedef unsigned int u32;

using f32x4  = __attribute__((ext_vector_type(4))) float;
using bf16x8 = __attribute__((ext_vector_type(8))) __bf16;

#define DEV __device__ __forceinline__

DEV u16 f2bf(float f) {                       // RTNE f32 -> bf16
  union { float f; u32 u; } x; x.f = f;
  return (u16)((x.u + 0x7fffu + ((x.u >> 16) & 1u)) >> 16);
}
DEV float bf2f(u16 h) {
  union { u32 u; float f; } x; x.u = ((u32)h) << 16;
  return x.f;
}

DEV void async_cp16(const u16* g, u16* l) {   // 16B global -> LDS direct
  __builtin_amdgcn_global_load_lds((const __attribute__((address_space(1))) void*)g,
                                   (__attribute__((address_space(3))) void*)l,
                                   16, 0, 0);
}

static constexpr int BATCH = 4096;
static constexpr int FEAT  = 512;
static constexpr int EMB   = 64;
static constexpr int HID   = 1024;
static constexpr int NC    = 64;
static constexpr int DIN   = 576;   // FEAT + EMB
static constexpr int LIB   = 256;   // LIB_X == LIB_Y == OUT_J
static constexpr int NBLK  = 512;   // persistent grid: exactly 2 blocks/CU

// ---- cheap per-block dtype / index-width detection (1 load/thread) ---------
DEV void detect_lite(const u32* __restrict__ sraw, const u32* __restrict__ oraw,
                     int* isf32, int* ostr) {
  __shared__ int cib, conz;
  const int t = threadIdx.x;
  if (t == 0) { cib = 0; conz = 0; }
  u32 w = sraw[t];
  u32 e = (w >> 7) & 0xFFu;
  unsigned long long m1 = __ballot(e >= 100 && e <= 142);
  unsigned long long m2 = __ballot((t & 1) && oraw[t] != 0);
  __syncthreads();
  if ((t & 63) == 0) {
    atomicAdd(&cib, __popcll(m1));
    atomicAdd(&conz, __popcll(m2));
  }
  __syncthreads();
  *isf32 = (cib < 128) ? 1 : 0;               // low halves not bf16-like -> f32
  *ostr  = (conz == 0) ? 2 : 1;               // all odd words zero -> int64
}

// ---- device-scope grid barrier (sense = monotonic gate) --------------------
// sync[0..2]: per-phase arrival counters (zeroed by in-graph memset);
// sync[3]: gate, set to `phase` by the last arriver.
DEV void grid_sync(int* sync, int phase) {
  __syncthreads();
  if (threadIdx.x == 0) {
    __threadfence();                          // release all prior stores
    int v = __hip_atomic_fetch_add(&sync[phase - 1], 1,
                                   __ATOMIC_ACQ_REL, __HIP_MEMORY_SCOPE_AGENT);
    if (v == NBLK - 1) {
      __hip_atomic_store(&sync[3], phase, __ATOMIC_RELEASE,
                         __HIP_MEMORY_SCOPE_AGENT);
    } else {
      while (__hip_atomic_load(&sync[3], __ATOMIC_ACQUIRE,
                               __HIP_MEMORY_SCOPE_AGENT) < phase)
        __builtin_amdgcn_s_sleep(2);
    }
    __threadfence();                          // acquire before subsequent loads
  }
  __syncthreads();
}

// ---- 64x64 transpose tile (bf16-ifying), vectorized both directions --------
DEV void do_transpose64(u16* lds, const void* __restrict__ in, size_t in_off,
                        u16* __restrict__ out, int R, int C,
                        int by, int bx, int isf32) {
  u16* tile = lds;                            // 64*72 u16
  const int t = threadIdx.x;
  __syncthreads();                            // protect LDS reuse across tasks
  {
    const int r = t >> 2, c0 = (t & 3) * 16;
    size_t off = in_off + (size_t)(by * 64 + r) * C + (bx * 64 + c0);
    u16 v[16];
    if (isf32) {
      const float4* s = (const float4*)((const float*)in + off);
      float4 a0 = s[0], a1 = s[1], a2 = s[2], a3 = s[3];
      v[0] = f2bf(a0.x); v[1] = f2bf(a0.y); v[2]  = f2bf(a0.z); v[3]  = f2bf(a0.w);
      v[4] = f2bf(a1.x); v[5] = f2bf(a1.y); v[6]  = f2bf(a1.z); v[7]  = f2bf(a1.w);
      v[8] = f2bf(a2.x); v[9] = f2bf(a2.y); v[10] = f2bf(a2.z); v[11] = f2bf(a2.w);
      v[12] = f2bf(a3.x); v[13] = f2bf(a3.y); v[14] = f2bf(a3.z); v[15] = f2bf(a3.w);
    } else {
      const uint4* s = (const uint4*)((const u16*)in + off);
      *(uint4*)&v[0] = s[0];
      *(uint4*)&v[8] = s[1];
    }
    *(uint4*)&tile[r * 72 + c0]     = *(uint4*)&v[0];
    *(uint4*)&tile[r * 72 + c0 + 8] = *(uint4*)&v[8];
  }
  __syncthreads();
  {
    const int c = t & 63, rs = (t >> 6) * 16;
    u16 w[16];
#pragma unroll
    for (int i = 0; i < 16; ++i) w[i] = tile[(rs + i) * 72 + c];
    size_t oo = (size_t)(bx * 64 + c) * R + (by * 64 + rs);
    *(uint4*)&out[oo]     = *(uint4*)&w[0];
    *(uint4*)&out[oo + 8] = *(uint4*)&w[8];
  }
}

// ---- generic bt-GEMM tile, BK=64 dual-slab: C=act(A[M,K]*Bt[N,K]^T+bias) ---
template <int BM, int BN, bool RELU>
DEV void gemm_tile(u16* lds, const u16* __restrict__ A, const u16* __restrict__ Bt,
                   const void* bias, void* C, int N, int K, int m0, int n0,
                   int isf32, bool cf32) {
  constexpr int WM = BM / 2, WN = BN / 2, TM = WM / 16, TN = WN / 16;
  u16* As = lds;                  // [2][BM][32]
  u16* Bs = lds + BM * 64;        // [2][BN][32]
  const int t = threadIdx.x;
  const int lane = t & 63, wid = t >> 6;
  const int wm = wid >> 1, wn = wid & 1;
  const int lr = lane & 15, lq = lane >> 4;
  f32x4 acc[TM][TN] = {};
  for (int k0 = 0; k0 < K; k0 += 64) {
    __syncthreads();
#pragma unroll
    for (int sl = 0; sl < 2; ++sl) {
#pragma unroll
      for (int u = 0; u < BM / 64; ++u) {
        int unit = u * 256 + t;
        int r = unit >> 2, c8 = (unit & 3) * 8;
        async_cp16(A + (size_t)(m0 + r) * K + (k0 + sl * 32 + c8),
                   &As[(sl * BM + r) * 32 + c8]);
      }
#pragma unroll
      for (int u = 0; u < BN / 64; ++u) {
        int unit = u * 256 + t;
        int r = unit >> 2, c8 = (unit & 3) * 8;
        async_cp16(Bt + (size_t)(n0 + r) * K + (k0 + sl * 32 + c8),
                   &Bs[(sl * BN + r) * 32 + c8]);
      }
    }
    __syncthreads();                          // drains vmcnt before ds_reads
#pragma unroll
    for (int sl = 0; sl < 2; ++sl) {
      bf16x8 av[TM], bv[TN];
#pragma unroll
      for (int i = 0; i < TM; ++i)
        av[i] = *(const bf16x8*)&As[(sl * BM + wm * WM + i * 16 + lr) * 32 + lq * 8];
#pragma unroll
      for (int j = 0; j < TN; ++j)
        bv[j] = *(const bf16x8*)&Bs[(sl * BN + wn * WN + j * 16 + lr) * 32 + lq * 8];
#pragma unroll
      for (int i = 0; i < TM; ++i)
#pragma unroll
        for (int j = 0; j < TN; ++j)
          acc[i][j] = __builtin_amdgcn_mfma_f32_16x16x32_bf16(av[i], bv[j], acc[i][j], 0, 0, 0);
    }
  }
  // epilogue: C/D layout col=lane&15, row=(lane>>4)*4+r  [m89/m91 verified]
#pragma unroll
  for (int j = 0; j < TN; ++j) {
    const int gc = n0 + wn * WN + j * 16 + lr;
    const float bval = bias
        ? (isf32 ? ((const float*)bias)[gc] : bf2f(((const u16*)bias)[gc]))
        : 0.f;
#pragma unroll
    for (int i = 0; i < TM; ++i) {
      const int gr = m0 + wm * WM + i * 16 + lq * 4;
#pragma unroll
      for (int r = 0; r < 4; ++r) {
        float v = acc[i][j][r] + bval;
        if (RELU) v = fmaxf(v, 0.f);
        const size_t idx = (size_t)(gr + r) * N + gc;
        if (cf32) ((float*)C)[idx] = v;
        else      ((u16*)C)[idx] = f2bf(v);
      }
    }
  }
}

// ---- the whole net as one persistent kernel --------------------------------
struct Args {
  const void *state, *emb, *Wx1, *bx1, *Wx2, *bx2, *Wy1, *by1, *Wy2, *by2, *nX, *nY;
  const int* opt;
  u16 *all_state, *h_x, *h_y, *cls_x, *cls_y, *WT1x, *WT1y, *WT2x, *WT2y, *XT, *YT;
  void* out;
  int* sync;
};

static constexpr int PT_CONCAT = 576;                        // concat tasks
static constexpr int PT_WT1 = 144, PT_WT2 = 64, PT_XT = 16, PT_YT = 1024;
static constexpr int PT_TOTAL = PT_CONCAT + 2 * PT_WT1 + 2 * PT_WT2
                              + PT_XT + PT_YT;               // 2032

__global__ __launch_bounds__(256, 2) void fused_k(Args a) {
  // LDS union: prep 4608 | gemm1 16384 | gemm2/noiseX 8192 | gather 25216 u16
  __shared__ __align__(16) u16 lds[25600];
  const int t = threadIdx.x, bid = blockIdx.x;
  int isf32, os;
  detect_lite((const u32*)a.state, (const u32*)a.opt, &isf32, &os);

  // ============ stage P: prep (2032 tasks over 512 blocks) ==================
  for (int task = bid; task < PT_TOTAL; task += NBLK) {
    int id = task;
    if (id < PT_CONCAT) {
      // concat: all_state[b] = [state[b], embed[option[b]]], 16 bf16/thread
      int idx = id * 256 + t;
      int b = idx / 36, ch = idx % 36;
      const void* base;
      size_t srcoff;
      if (ch < 32) { base = a.state; srcoff = (size_t)b * FEAT + ch * 16; }
      else {
        base = a.emb;
        srcoff = (size_t)a.opt[(size_t)b * os] * EMB + (ch - 32) * 16;
      }
      u16 o[16];
      if (isf32) {
        const float4* s = (const float4*)((const float*)base + srcoff);
        float4 a0 = s[0], a1 = s[1], a2 = s[2], a3 = s[3];
        o[0] = f2bf(a0.x); o[1] = f2bf(a0.y); o[2]  = f2bf(a0.z); o[3]  = f2bf(a0.w);
        o[4] = f2bf(a1.x); o[5] = f2bf(a1.y); o[6]  = f2bf(a1.z); o[7]  = f2bf(a1.w);
        o[8] = f2bf(a2.x); o[9] = f2bf(a2.y); o[10] = f2bf(a2.z); o[11] = f2bf(a2.w);
        o[12] = f2bf(a3.x); o[13] = f2bf(a3.y); o[14] = f2bf(a3.z); o[15] = f2bf(a3.w);
      } else {
        const uint4* s = (const uint4*)((const u16*)base + srcoff);
        *(uint4*)&o[0] = s[0];
        *(uint4*)&o[8] = s[1];
      }
      u16* dst = a.all_state + (size_t)b * DIN + ch * 16;
      *(uint4*)dst       = *(const uint4*)&o[0];
      *(uint4*)(dst + 8) = *(const uint4*)&o[8];
      continue;
    }
    id -= PT_CONCAT;
    if (id < PT_WT1) { do_transpose64(lds, a.Wx1, 0, a.WT1x, DIN, HID, id >> 4, id & 15, isf32); continue; }
    id -= PT_WT1;
    if (id < PT_WT1) { do_transpose64(lds, a.Wy1, 0, a.WT1y, DIN, HID, id >> 4, id & 15, isf32); continue; }
    id -= PT_WT1;
    if (id < PT_WT2) { do_transpose64(lds, a.Wx2, 0, a.WT2x, HID, LIB, id >> 2, id & 3, isf32); continue; }
    id -= PT_WT2;
    if (id < PT_WT2) { do_transpose64(lds, a.Wy2, 0, a.WT2y, HID, LIB, id >> 2, id & 3, isf32); continue; }
    id -= PT_WT2;
    if (id < PT_XT) { do_transpose64(lds, a.nX, 0, a.XT, LIB, LIB, id >> 2, id & 3, isf32); continue; }
    id -= PT_XT;
    {
      int z = id >> 4, sub = id & 15;
      do_transpose64(lds, a.nY, (size_t)z * LIB * LIB, a.YT + (size_t)z * LIB * LIB,
                     LIB, LIB, sub >> 2, sub & 3, isf32);
    }
  }
  grid_sync(a.sync, 1);

  // ============ stage 1: layer-1 GEMM (relu), 512 = 2 heads x 32m x 8n ======
  {
    const int head = bid >> 8, r = bid & 255;
    const int m0 = (r >> 3) * 128, n0 = (r & 7) * 128;
    gemm_tile<128, 128, true>(lds,
        a.all_state, head ? a.WT1y : a.WT1x, head ? a.by1 : a.bx1,
        head ? a.h_y : a.h_x, HID, DIN, m0, n0, isf32, false);
  }
  grid_sync(a.sync, 2);

  // ============ stage 2: layer-2 GEMM, 512 = 2 heads x 64m x 4n =============
  {
    const int head = bid >> 8, r = bid & 255;
    const int m0 = (r >> 2) * 64, n0 = (r & 3) * 64;
    gemm_tile<64, 64, false>(lds,
        head ? a.h_y : a.h_x, head ? a.WT2y : a.WT2x, head ? a.by2 : a.bx2,
        head ? a.cls_y : a.cls_x, LIB, HID, m0, n0, isf32, false);
  }
  grid_sync(a.sync, 3);

  // ============ stage 3: noiseX (256 blocks) + routed gatherY (256) =========
  const bool of32 = (isf32 != 0);
  if (bid < 256) {
    const int m0 = (bid >> 2) * 64, n0 = (bid & 3) * 64;
    gemm_tile<64, 64, false>(lds, a.cls_x, a.XT, nullptr, a.out,
                             LIB, LIB, m0, n0, isf32, of32);
    return;
  }
  {
    u16* Bts = lds;               // 64 x 264
    u16* Asm = lds + 16896;       // 16 x 264
    u16* list = lds + 21120;      // up to 4096 row ids (u16)
    __shared__ int lcnt;
    const int rb = bid - 256;
    const int m = rb >> 2, n0 = (rb & 3) * 64;
    const int lane = t & 63, w = t >> 6, lr = lane & 15, lq = lane >> 4;
    // stage Y[m]^T tile once (+8 pad)
    {
      const int r = t >> 2, cb = (t & 3) * 64;
      const u16* src = a.YT + (size_t)m * LIB * LIB + (size_t)(n0 + r) * LIB + cb;
      u16* dst = &Bts[r * 264 + cb];
#pragma unroll
      for (int v = 0; v < 8; ++v)
        *(uint4*)(dst + v * 8) = *(const uint4*)(src + v * 8);
    }
    // self-build row list for class m (order-free compaction)
    if (t == 0) lcnt = 0;
    __syncthreads();
    for (int base = 0; base < BATCH; base += 256) {
      int e = a.opt[(size_t)(base + t) * os];
      if (e == m) { int p = atomicAdd(&lcnt, 1); list[p] = (u16)(base + t); }
    }
    __syncthreads();
    const int cnt = lcnt;
    const size_t out_off = (size_t)BATCH * LIB;
    for (int ch = 0; ch < cnt; ch += 16) {
      __syncthreads();
      {
        const int r = t >> 4, cb = (t & 15) * 16;
        if (ch + r < cnt) {
          const u16* src = a.cls_y + (size_t)list[ch + r] * LIB + cb;
          *(uint4*)&Asm[r * 264 + cb]     = *(const uint4*)src;
          *(uint4*)&Asm[r * 264 + cb + 8] = *(const uint4*)(src + 8);
        } else {
          uint4 z{0, 0, 0, 0};
          *(uint4*)&Asm[r * 264 + cb]     = z;
          *(uint4*)&Asm[r * 264 + cb + 8] = z;
        }
      }
      __syncthreads();
      f32x4 acc = {};
#pragma unroll
      for (int kk = 0; kk < LIB; kk += 32) {
        bf16x8 av = *(const bf16x8*)&Asm[lr * 264 + kk + lq * 8];
        bf16x8 bv = *(const bf16x8*)&Bts[(w * 16 + lr) * 264 + kk + lq * 8];
        acc = __builtin_amdgcn_mfma_f32_16x16x32_bf16(av, bv, acc, 0, 0, 0);
      }
#pragma unroll
      for (int r = 0; r < 4; ++r) {
        const int rowc = lq * 4 + r;
        if (ch + rowc < cnt) {
          const size_t oi = out_off + (size_t)list[ch + rowc] * LIB
                          + (n0 + w * 16 + lr);
          if (of32) ((float*)a.out)[oi] = acc[r];
          else      ((u16*)a.out)[oi] = f2bf(acc[r]);
        }
      }
    }
  }
}

extern "C" void kernel_launch(void* const* d_in, const int* in_sizes, int n_in,
                              void* d_out, int out_size, void* d_ws, size_t ws_size,
                              hipStream_t stream) {
  char* p = (char*)d_ws;
  auto alloc = [&](size_t bytes) { char* r = p; p += (bytes + 255) & ~(size_t)255; return r; };
  int* sync  = (int*)alloc(64);
  u16* all_state = (u16*)alloc((size_t)BATCH * DIN * 2);
  u16* h_x   = (u16*)alloc((size_t)BATCH * HID * 2);
  u16* h_y   = (u16*)alloc((size_t)BATCH * HID * 2);
  u16* cls_x = (u16*)alloc((size_t)BATCH * LIB * 2);
  u16* cls_y = (u16*)alloc((size_t)BATCH * LIB * 2);
  u16* WT1x  = (u16*)alloc((size_t)HID * DIN * 2);
  u16* WT1y  = (u16*)alloc((size_t)HID * DIN * 2);
  u16* WT2x  = (u16*)alloc((size_t)LIB * HID * 2);
  u16* WT2y  = (u16*)alloc((size_t)LIB * HID * 2);
  u16* XT    = (u16*)alloc((size_t)LIB * LIB * 2);
  u16* YT    = (u16*)alloc((size_t)NC * LIB * LIB * 2);

  Args a;
  a.state = d_in[0]; a.opt = (const int*)d_in[1]; a.emb = d_in[2];
  a.Wx1 = d_in[3]; a.bx1 = d_in[4]; a.Wx2 = d_in[5]; a.bx2 = d_in[6];
  a.Wy1 = d_in[7]; a.by1 = d_in[8]; a.Wy2 = d_in[9]; a.by2 = d_in[10];
  a.nX = d_in[11]; a.nY = d_in[12];
  a.all_state = all_state; a.h_x = h_x; a.h_y = h_y;
  a.cls_x = cls_x; a.cls_y = cls_y;
  a.WT1x = WT1x; a.WT1y = WT1y; a.WT2x = WT2x; a.WT2y = WT2y;
  a.XT = XT; a.YT = YT;
  a.out = d_out; a.sync = sync;

  hipMemsetAsync(sync, 0, 64, stream);        // zero grid-barrier state (in-graph)
  fused_k<<<NBLK, 256, 0, stream>>>(a);
}

// Round 6
// 156.622 us; speedup vs baseline: 2.5073x; 2.5073x over previous
//
#include <hip/hip_runtime.h>

typedef unsigned short u16;
typedef unsigned int u32;

using f32x4  = __attribute__((ext_vector_type(4))) float;
using bf16x8 = __attribute__((ext_vector_type(8))) __bf16;

#define DEV __device__ __forceinline__

DEV u16 f2bf(float f) {                       // RTNE f32 -> bf16
  union { float f; u32 u; } x; x.f = f;
  return (u16)((x.u + 0x7fffu + ((x.u >> 16) & 1u)) >> 16);
}
DEV float bf2f(u16 h) {
  union { u32 u; float f; } x; x.u = ((u32)h) << 16;
  return x.f;
}

DEV void async_cp16(const u16* g, u16* l) {   // 16B global -> LDS direct
  __builtin_amdgcn_global_load_lds((const __attribute__((address_space(1))) void*)g,
                                   (__attribute__((address_space(3))) void*)l,
                                   16, 0, 0);
}

static constexpr int BATCH = 4096;
static constexpr int FEAT  = 512;
static constexpr int EMB   = 64;
static constexpr int HID   = 1024;
static constexpr int NC    = 64;
static constexpr int DIN   = 576;   // FEAT + EMB
static constexpr int LIB   = 256;   // LIB_X == LIB_Y == OUT_J

// ---- cheap per-block dtype / index-width detection (1 load/thread) ---------
// Self-contained per block: no cross-launch flag dependency. bf16 storage ->
// ~256/256 low-half exponents in [100,142]; f32 -> ~17%. int64 option -> all
// odd u32 words zero.
DEV void detect_lite(const u32* __restrict__ sraw, const u32* __restrict__ oraw,
                     int* isf32, int* ostr) {
  __shared__ int cib, conz;
  const int t = threadIdx.x;
  if (t == 0) { cib = 0; conz = 0; }
  u32 w = sraw[t];
  u32 e = (w >> 7) & 0xFFu;
  unsigned long long m1 = __ballot(e >= 100 && e <= 142);
  unsigned long long m2 = __ballot((t & 1) && oraw[t] != 0);
  __syncthreads();
  if ((t & 63) == 0) {
    atomicAdd(&cib, __popcll(m1));
    atomicAdd(&conz, __popcll(m2));
  }
  __syncthreads();
  *isf32 = (cib < 128) ? 1 : 0;
  *ostr  = (conz == 0) ? 2 : 1;
}

// ---- 64x64 transpose tile (bf16-ifying), vectorized both directions --------
DEV void do_transpose64(const void* __restrict__ in, size_t in_off,
                        u16* __restrict__ out, int R, int C,
                        int by, int bx, int isf32) {
  __shared__ u16 tile[64 * 72];
  const int t = threadIdx.x;
  {
    const int r = t >> 2, c0 = (t & 3) * 16;
    size_t off = in_off + (size_t)(by * 64 + r) * C + (bx * 64 + c0);
    u16 v[16];
    if (isf32) {
      const float4* s = (const float4*)((const float*)in + off);
      float4 a0 = s[0], a1 = s[1], a2 = s[2], a3 = s[3];
      v[0] = f2bf(a0.x); v[1] = f2bf(a0.y); v[2]  = f2bf(a0.z); v[3]  = f2bf(a0.w);
      v[4] = f2bf(a1.x); v[5] = f2bf(a1.y); v[6]  = f2bf(a1.z); v[7]  = f2bf(a1.w);
      v[8] = f2bf(a2.x); v[9] = f2bf(a2.y); v[10] = f2bf(a2.z); v[11] = f2bf(a2.w);
      v[12] = f2bf(a3.x); v[13] = f2bf(a3.y); v[14] = f2bf(a3.z); v[15] = f2bf(a3.w);
    } else {
      const uint4* s = (const uint4*)((const u16*)in + off);
      *(uint4*)&v[0] = s[0];
      *(uint4*)&v[8] = s[1];
    }
    *(uint4*)&tile[r * 72 + c0]     = *(uint4*)&v[0];
    *(uint4*)&tile[r * 72 + c0 + 8] = *(uint4*)&v[8];
  }
  __syncthreads();
  {
    const int c = t & 63, rs = (t >> 6) * 16;
    u16 w[16];
#pragma unroll
    for (int i = 0; i < 16; ++i) w[i] = tile[(rs + i) * 72 + c];
    size_t oo = (size_t)(bx * 64 + c) * R + (by * 64 + rs);
    *(uint4*)&out[oo]     = *(uint4*)&w[0];
    *(uint4*)&out[oo + 8] = *(uint4*)&w[8];
  }
}

// ---- prep: concat | 4 weight transposes | XT transpose (no sort, no YT) ----
struct PrepArgs {
  const void *state, *emb, *Wx1, *Wy1, *Wx2, *Wy2, *nX;
  const int* opt;
  u16 *all_state, *WT1x, *WT1y, *WT2x, *WT2y, *XT;
};
static constexpr int PB_CONCAT = BATCH * 36 / 256;            // 576
static constexpr int PB_WT1 = (DIN / 64) * (HID / 64);        // 144
static constexpr int PB_WT2 = (HID / 64) * (LIB / 64);        // 64
static constexpr int PB_XT  = (LIB / 64) * (LIB / 64);        // 16
static constexpr int PREP_BLOCKS = PB_CONCAT + 2 * PB_WT1 + 2 * PB_WT2 + PB_XT; // 1008

__global__ __launch_bounds__(256) void prep_k(PrepArgs a) {
  int isf32, os;
  detect_lite((const u32*)a.state, (const u32*)a.opt, &isf32, &os);
  int bid = blockIdx.x;
  if (bid < PB_CONCAT) {
    // concat: all_state[b] = [state[b], embed[option[b]]], 16 bf16/thread
    int idx = bid * 256 + threadIdx.x;
    int b = idx / 36, ch = idx % 36;
    const void* base;
    size_t srcoff;
    if (ch < 32) { base = a.state; srcoff = (size_t)b * FEAT + ch * 16; }
    else {
      base = a.emb;
      srcoff = (size_t)a.opt[(size_t)b * os] * EMB + (ch - 32) * 16;
    }
    u16 o[16];
    if (isf32) {
      const float4* s = (const float4*)((const float*)base + srcoff);
      float4 a0 = s[0], a1 = s[1], a2 = s[2], a3 = s[3];
      o[0] = f2bf(a0.x); o[1] = f2bf(a0.y); o[2]  = f2bf(a0.z); o[3]  = f2bf(a0.w);
      o[4] = f2bf(a1.x); o[5] = f2bf(a1.y); o[6]  = f2bf(a1.z); o[7]  = f2bf(a1.w);
      o[8] = f2bf(a2.x); o[9] = f2bf(a2.y); o[10] = f2bf(a2.z); o[11] = f2bf(a2.w);
      o[12] = f2bf(a3.x); o[13] = f2bf(a3.y); o[14] = f2bf(a3.z); o[15] = f2bf(a3.w);
    } else {
      const uint4* s = (const uint4*)((const u16*)base + srcoff);
      *(uint4*)&o[0] = s[0];
      *(uint4*)&o[8] = s[1];
    }
    u16* dst = a.all_state + (size_t)b * DIN + ch * 16;
    *(uint4*)dst       = *(const uint4*)&o[0];
    *(uint4*)(dst + 8) = *(const uint4*)&o[8];
    return;
  }
  bid -= PB_CONCAT;
  if (bid < PB_WT1) { do_transpose64(a.Wx1, 0, a.WT1x, DIN, HID, bid >> 4, bid & 15, isf32); return; }
  bid -= PB_WT1;
  if (bid < PB_WT1) { do_transpose64(a.Wy1, 0, a.WT1y, DIN, HID, bid >> 4, bid & 15, isf32); return; }
  bid -= PB_WT1;
  if (bid < PB_WT2) { do_transpose64(a.Wx2, 0, a.WT2x, HID, LIB, bid >> 2, bid & 3, isf32); return; }
  bid -= PB_WT2;
  if (bid < PB_WT2) { do_transpose64(a.Wy2, 0, a.WT2y, HID, LIB, bid >> 2, bid & 3, isf32); return; }
  bid -= PB_WT2;
  do_transpose64(a.nX, 0, a.XT, LIB, LIB, bid >> 2, bid & 3, isf32);
}

// ---- bt-GEMM tile, BK=64 dual-slab (r5-validated): C=act(A*Bt^T+bias) ------
template <int BM, int BN, bool RELU>
DEV void gemm_tile(u16* lds, const u16* __restrict__ A, const u16* __restrict__ Bt,
                   const void* bias, void* C, int N, int K, int m0, int n0,
                   int isf32, bool cf32) {
  constexpr int WM = BM / 2, WN = BN / 2, TM = WM / 16, TN = WN / 16;
  u16* As = lds;                  // [2][BM][32]
  u16* Bs = lds + BM * 64;        // [2][BN][32]
  const int t = threadIdx.x;
  const int lane = t & 63, wid = t >> 6;
  const int wm = wid >> 1, wn = wid & 1;
  const int lr = lane & 15, lq = lane >> 4;
  f32x4 acc[TM][TN] = {};
  for (int k0 = 0; k0 < K; k0 += 64) {
    __syncthreads();
#pragma unroll
    for (int sl = 0; sl < 2; ++sl) {
#pragma unroll
      for (int u = 0; u < BM / 64; ++u) {
        int unit = u * 256 + t;
        int r = unit >> 2, c8 = (unit & 3) * 8;
        async_cp16(A + (size_t)(m0 + r) * K + (k0 + sl * 32 + c8),
                   &As[(sl * BM + r) * 32 + c8]);
      }
#pragma unroll
      for (int u = 0; u < BN / 64; ++u) {
        int unit = u * 256 + t;
        int r = unit >> 2, c8 = (unit & 3) * 8;
        async_cp16(Bt + (size_t)(n0 + r) * K + (k0 + sl * 32 + c8),
                   &Bs[(sl * BN + r) * 32 + c8]);
      }
    }
    __syncthreads();
#pragma unroll
    for (int sl = 0; sl < 2; ++sl) {
      bf16x8 av[TM], bv[TN];
#pragma unroll
      for (int i = 0; i < TM; ++i)
        av[i] = *(const bf16x8*)&As[(sl * BM + wm * WM + i * 16 + lr) * 32 + lq * 8];
#pragma unroll
      for (int j = 0; j < TN; ++j)
        bv[j] = *(const bf16x8*)&Bs[(sl * BN + wn * WN + j * 16 + lr) * 32 + lq * 8];
#pragma unroll
      for (int i = 0; i < TM; ++i)
#pragma unroll
        for (int j = 0; j < TN; ++j)
          acc[i][j] = __builtin_amdgcn_mfma_f32_16x16x32_bf16(av[i], bv[j], acc[i][j], 0, 0, 0);
    }
  }
  // epilogue: C/D layout col=lane&15, row=(lane>>4)*4+r  [m89/m91 verified]
#pragma unroll
  for (int j = 0; j < TN; ++j) {
    const int gc = n0 + wn * WN + j * 16 + lr;
    const float bval = bias
        ? (isf32 ? ((const float*)bias)[gc] : bf2f(((const u16*)bias)[gc]))
        : 0.f;
#pragma unroll
    for (int i = 0; i < TM; ++i) {
      const int gr = m0 + wm * WM + i * 16 + lq * 4;
#pragma unroll
      for (int r = 0; r < 4; ++r) {
        float v = acc[i][j][r] + bval;
        if (RELU) v = fmaxf(v, 0.f);
        const size_t idx = (size_t)(gr + r) * N + gc;
        if (cf32) ((float*)C)[idx] = v;
        else      ((u16*)C)[idx] = f2bf(v);
      }
    }
  }
}

struct GArg { const u16* A; const u16* Bt; const void* bias; void* C; int cflag; };

template <int BM, int BN, bool RELU>
__global__ __launch_bounds__(256) void gemm_bt(GArg g0, GArg g1, int N, int K,
                                               const void* state, const void* opt) {
  __shared__ __align__(16) u16 lds[(BM + BN) * 64];
  int isf32, os;
  detect_lite((const u32*)state, (const u32*)opt, &isf32, &os);
  const GArg g = blockIdx.z ? g1 : g0;
  gemm_tile<BM, BN, RELU>(lds, g.A, g.Bt, g.bias, g.C, N, K,
                          blockIdx.y * BM, blockIdx.x * BN,
                          isf32, g.cflag && isf32);
}

// ---- tail: blocks 0..255 noiseX gemm; 256..511 routed gatherY --------------
// gatherY stages B directly from nY (fused f32->bf16 + transpose, no YT), and
// builds its class row-list via ballot prefix compaction (no sort kernel).
struct TailArgs {
  const u16 *cls_x, *XT, *cls_y;
  const void *nY, *state;
  const int* opt;
  void* out;            // out0 at 0, out1 at BATCH*LIB
};

__global__ __launch_bounds__(256) void tail_k(TailArgs a) {
  __shared__ __align__(16) u16 lds[25216];  // Bts 64x264 | Asm 16x264 | list 4096
  __shared__ int wcnt[4], lbase;
  int isf32, os;
  detect_lite((const u32*)a.state, (const u32*)a.opt, &isf32, &os);
  const bool of32 = (isf32 != 0);
  const int t = threadIdx.x;
  const int lane = t & 63, w = t >> 6, lr = lane & 15, lq = lane >> 4;

  if (blockIdx.x < 256) {
    // ---- noiseX: 64x64 bt-gemm, C = cls_x[4096,256] * XT[256,256]^T --------
    const int m0 = (blockIdx.x >> 2) * 64, n0 = (blockIdx.x & 3) * 64;
    gemm_tile<64, 64, false>(lds, a.cls_x, a.XT, nullptr, a.out,
                             LIB, LIB, m0, n0, isf32, of32);
    return;
  }

  // ---- routed gatherY: one block per (class m, 64-col tile) ----------------
  u16* Bts  = lds;            // [64][264]  B[n][k] = nY[m][k][n0+n]
  u16* Asm  = lds + 16896;    // [16][264]
  u16* list = lds + 21120;    // up to 4096 row ids
  const int rb = blockIdx.x - 256;
  const int m = rb >> 2, n0 = (rb & 3) * 64;

  // stage B with fused convert+transpose (scatter writes ~2-way banks = free)
#pragma unroll
  for (int pass = 0; pass < 4; ++pass) {
    const int k = pass * 64 + (t >> 2), nc = (t & 3) * 16;
    const size_t off = ((size_t)m * LIB + k) * LIB + n0 + nc;
    u16 v[16];
    if (isf32) {
      const float4* s = (const float4*)((const float*)a.nY + off);
      float4 a0 = s[0], a1 = s[1], a2 = s[2], a3 = s[3];
      v[0] = f2bf(a0.x); v[1] = f2bf(a0.y); v[2]  = f2bf(a0.z); v[3]  = f2bf(a0.w);
      v[4] = f2bf(a1.x); v[5] = f2bf(a1.y); v[6]  = f2bf(a1.z); v[7]  = f2bf(a1.w);
      v[8] = f2bf(a2.x); v[9] = f2bf(a2.y); v[10] = f2bf(a2.z); v[11] = f2bf(a2.w);
      v[12] = f2bf(a3.x); v[13] = f2bf(a3.y); v[14] = f2bf(a3.z); v[15] = f2bf(a3.w);
    } else {
      const uint4* s = (const uint4*)((const u16*)a.nY + off);
      *(uint4*)&v[0] = s[0];
      *(uint4*)&v[8] = s[1];
    }
#pragma unroll
    for (int j = 0; j < 16; ++j) Bts[(nc + j) * 264 + k] = v[j];
  }

  // build row list for class m: ballot + wave-prefix compaction (b-ordered)
  if (t == 0) lbase = 0;
  __syncthreads();
  for (int base = 0; base < BATCH; base += 256) {
    const int b = base + t;
    const int e = a.opt[(size_t)b * os];
    unsigned long long mk = __ballot(e == m);
    if (lane == 0) wcnt[w] = __popcll(mk);
    __syncthreads();
    int wpre = lbase;
    for (int i = 0; i < w; ++i) wpre += wcnt[i];
    const int mypre = __popcll(mk & ((1ull << lane) - 1ull));
    if (e == m) list[wpre + mypre] = (u16)b;
    __syncthreads();
    if (t == 0) lbase += wcnt[0] + wcnt[1] + wcnt[2] + wcnt[3];
  }
  __syncthreads();
  const int cnt = lbase;
  const size_t out_off = (size_t)BATCH * LIB;

  for (int ch = 0; ch < cnt; ch += 16) {
    __syncthreads();
    {
      const int r = t >> 4, cb = (t & 15) * 16;
      if (ch + r < cnt) {
        const u16* src = a.cls_y + (size_t)list[ch + r] * LIB + cb;
        *(uint4*)&Asm[r * 264 + cb]     = *(const uint4*)src;
        *(uint4*)&Asm[r * 264 + cb + 8] = *(const uint4*)(src + 8);
      } else {
        uint4 z{0, 0, 0, 0};
        *(uint4*)&Asm[r * 264 + cb]     = z;
        *(uint4*)&Asm[r * 264 + cb + 8] = z;
      }
    }
    __syncthreads();
    f32x4 acc = {};
#pragma unroll
    for (int kk = 0; kk < LIB; kk += 32) {
      bf16x8 av = *(const bf16x8*)&Asm[lr * 264 + kk + lq * 8];
      bf16x8 bv = *(const bf16x8*)&Bts[(w * 16 + lr) * 264 + kk + lq * 8];
      acc = __builtin_amdgcn_mfma_f32_16x16x32_bf16(av, bv, acc, 0, 0, 0);
    }
#pragma unroll
    for (int r = 0; r < 4; ++r) {
      const int rowc = lq * 4 + r;
      if (ch + rowc < cnt) {
        const size_t oi = out_off + (size_t)list[ch + rowc] * LIB
                        + (n0 + w * 16 + lr);
        if (of32) ((float*)a.out)[oi] = acc[r];
        else      ((u16*)a.out)[oi] = f2bf(acc[r]);
      }
    }
  }
}

extern "C" void kernel_launch(void* const* d_in, const int* in_sizes, int n_in,
                              void* d_out, int out_size, void* d_ws, size_t ws_size,
                              hipStream_t stream) {
  char* p = (char*)d_ws;
  auto alloc = [&](size_t bytes) { char* r = p; p += (bytes + 255) & ~(size_t)255; return r; };
  u16* all_state = (u16*)alloc((size_t)BATCH * DIN * 2);
  u16* h_x   = (u16*)alloc((size_t)BATCH * HID * 2);
  u16* h_y   = (u16*)alloc((size_t)BATCH * HID * 2);
  u16* cls_x = (u16*)alloc((size_t)BATCH * LIB * 2);
  u16* cls_y = (u16*)alloc((size_t)BATCH * LIB * 2);
  u16* WT1x  = (u16*)alloc((size_t)HID * DIN * 2);
  u16* WT1y  = (u16*)alloc((size_t)HID * DIN * 2);
  u16* WT2x  = (u16*)alloc((size_t)LIB * HID * 2);
  u16* WT2y  = (u16*)alloc((size_t)LIB * HID * 2);
  u16* XT    = (u16*)alloc((size_t)LIB * LIB * 2);

  const void* state = d_in[0];
  const void* opt   = d_in[1];

  // 1) prep: concat + 4 weight transposes + XT (1008 fully parallel blocks)
  PrepArgs pa;
  pa.state = state; pa.opt = (const int*)opt; pa.emb = d_in[2];
  pa.Wx1 = d_in[3]; pa.Wx2 = d_in[5]; pa.Wy1 = d_in[7]; pa.Wy2 = d_in[9];
  pa.nX = d_in[11];
  pa.all_state = all_state; pa.WT1x = WT1x; pa.WT1y = WT1y;
  pa.WT2x = WT2x; pa.WT2y = WT2y; pa.XT = XT;
  prep_k<<<PREP_BLOCKS, 256, 0, stream>>>(pa);

  // 2) layer 1 (relu), X and Y heads via grid.z, BK=64
  GArg g1x{all_state, WT1x, d_in[4], h_x, 0}, g1y{all_state, WT1y, d_in[8], h_y, 0};
  gemm_bt<128, 128, true><<<dim3(HID / 128, BATCH / 128, 2), 256, 0, stream>>>(
      g1x, g1y, HID, DIN, state, opt);

  // 3) layer 2, 64x64 tiles, BK=64 (512 blocks = 2/CU)
  GArg g2x{h_x, WT2x, d_in[6], cls_x, 0}, g2y{h_y, WT2y, d_in[10], cls_y, 0};
  gemm_bt<64, 64, false><<<dim3(LIB / 64, BATCH / 64, 2), 256, 0, stream>>>(
      g2x, g2y, LIB, HID, state, opt);

  // 4) merged tail: noiseX gemm (256 blocks) + routed gatherY (256 blocks)
  TailArgs ta{cls_x, XT, cls_y, d_in[12], state, (const int*)opt, d_out};
  tail_k<<<512, 256, 0, stream>>>(ta);
}